// Round 4
// baseline (2204.297 us; speedup 1.0000x reference)
//
#include <hip/hip_runtime.h>
#include <cstddef>
#include <cstdint>

#define BATCH 32
#define CCH   512
#define OCH   1024
#define HW    3136
#define WDIM  56
#define NKT   16           // 512 / BK, BK=32

typedef __attribute__((ext_vector_type(8))) short short8v;  // 8 bf16
typedef __attribute__((ext_vector_type(4))) float f32x4;

// pair of fp32 -> packed bf16 hi-word + lo-word (R1-proven numerics).
static __device__ __forceinline__ void cvt2(float x0, float x1,
                                            unsigned& hw, unsigned& lw) {
    unsigned u0 = __float_as_uint(x0), u1 = __float_as_uint(x1);
    hw = (u1 & 0xffff0000u) | (u0 >> 16);
    float l0 = x0 - __uint_as_float(u0 & 0xffff0000u);
    float l1 = x1 - __uint_as_float(u1 & 0xffff0000u);
    unsigned r0 = __float_as_uint(l0), r1 = __float_as_uint(l1);
    r0 = r0 + 0x7fffu + ((r0 >> 16) & 1u);
    r1 = r1 + 0x7fffu + ((r1 >> 16) & 1u);
    lw = (r1 & 0xffff0000u) | (r0 >> 16);
}

static __device__ __forceinline__ int physlot(int s, int row) {
    return (s ^ (row & 7) ^ ((row >> 3) & 7)) & 7;
}

#define GLD_LDS16(gsrc, ldst) \
    __builtin_amdgcn_global_load_lds( \
        (const __attribute__((address_space(1))) void*)(gsrc), \
        (__attribute__((address_space(3))) void*)(ldst), 16, 0, 0)

// ---------------------------------------------------------------------------
// K0: pre-convert weights into LDS-image layout (R3-proven):
// wcvt[o][kt] = 128 B: phys slots 0-3 <- hi octets, 4-7 <- lo octets,
// pre-swizzled with physlot(s, o) so the GEMM can linear-copy.
// ---------------------------------------------------------------------------
__global__ __launch_bounds__(256) void preconv_w(
    const float* __restrict__ wp, unsigned char* __restrict__ wcvt)
{
    const int id = blockIdx.x * 256 + threadIdx.x;   // 16384 = 1024 o x 16 kt
    const int o = id >> 4, kt = id & 15;
    const float* p = wp + (size_t)o * CCH + kt * 32;
    unsigned char* dst = wcvt + (size_t)o * 2048 + kt * 128;
    float4 v[8];
#pragma unroll
    for (int r = 0; r < 8; ++r) v[r] = *(const float4*)(p + 4 * r);
#pragma unroll
    for (int oc = 0; oc < 4; ++oc) {
        unsigned h0, w0, h1, w1, h2, w2, h3, w3;
        cvt2(v[2*oc].x,   v[2*oc].y,   h0, w0);
        cvt2(v[2*oc].z,   v[2*oc].w,   h1, w1);
        cvt2(v[2*oc+1].x, v[2*oc+1].y, h2, w2);
        cvt2(v[2*oc+1].z, v[2*oc+1].w, h3, w3);
        *(uint4*)(dst + physlot(oc, o) * 16)     = make_uint4(h0, h1, h2, h3);
        *(uint4*)(dst + physlot(4 + oc, o) * 16) = make_uint4(w0, w1, w2, w3);
    }
}

// ---------------------------------------------------------------------------
// K1: MFMA GEMM, tile 256(o) x 128(n), BK=32, 256 threads = 4 waves (2x2 of
// 128x64). LDS 48KB -> 3 blocks/CU (12 waves) so barrier drains overlap
// across blocks. Flat grid 3200 with bijective XCD-chunk swizzle; the 4
// o-tiles of one (n,b) are adjacent in-chunk for L2 reuse of the B panel.
// ---------------------------------------------------------------------------
template <bool PRE>
__global__ __launch_bounds__(256, 3) void gemm_mfma(
    const float* __restrict__ in,          // [B,512,3136]
    const float* __restrict__ wp,          // [1024,512] (fallback path)
    const unsigned char* __restrict__ wc,  // wcvt (fast path)
    const float* __restrict__ bp,          // [1024]
    float* __restrict__ gate,              // d_out
    float* __restrict__ scan)              // ws (+2MB on fast path)
{
    // ---- bijective XCD-chunk swizzle: 3200 blocks = 8 chunks x 400 ----
    const int id  = blockIdx.x;
    const int swz = (id & 7) * 400 + (id >> 3);
    const int ot  = swz & 3;                 // o-tile (fastest in chunk)
    const int bx  = (swz >> 2) % 25;         // n-tile
    const int b   = swz / 100;               // batch

    const int t  = threadIdx.x;
    const int lane = t & 63;
    const int wid  = t >> 6;           // 0..3
    const int wm = wid >> 1;           // o-strip of 128
    const int wn = wid & 1;            // n-strip of 64
    const int l15 = lane & 15, lko = lane >> 4;

    __shared__ __align__(16) unsigned char lds[49152];   // A 32K | B 16K
    unsigned char* ldsB = lds + 32768;

    const int o0 = ot * 256;
    const int n0 = bx * 128;

    // B staging role: thread (q = n-quad, kg = k-group of 4)
    const int q  = t & 31;
    const int kg = t >> 5;             // 0..7
    const int maxq = ((HW - n0) >> 2) - 1;
    const int qc = q < maxq ? q : maxq;
    const float* inB = in + (size_t)b * (CCH * (size_t)HW) + n0 + 4 * qc;

    f32x4 acc[8][4] = {};

    float4 bc[4], bn[4];
    {   // B(0): 4 k-rows of this thread's k-group
        const float* p = inB + (size_t)(kg * 4) * HW;
#pragma unroll
        for (int r = 0; r < 4; ++r) bc[r] = *(const float4*)(p + (size_t)r * HW);
    }

#pragma unroll 1
    for (int kt = 0; kt < NKT; ++kt) {
        // ---- write B(kt) to LDS (16x b32 per thread) ----
        {
            const int oc = kg >> 1;            // k-octet
            const int wb = (kg & 1) * 2;       // word base within slot
            unsigned h0, l0, h1, l1;
#define BCOL(C, COMP) \
            { const int nl = 4 * q + C; \
              unsigned char* row = ldsB + nl * 128; \
              cvt2(bc[0].COMP, bc[1].COMP, h0, l0); \
              cvt2(bc[2].COMP, bc[3].COMP, h1, l1); \
              unsigned* ph = (unsigned*)(row + physlot(oc, nl) * 16); \
              unsigned* pl = (unsigned*)(row + physlot(4 + oc, nl) * 16); \
              ph[wb] = h0; ph[wb + 1] = h1; \
              pl[wb] = l0; pl[wb + 1] = l1; }
            BCOL(0, x) BCOL(1, y) BCOL(2, z) BCOL(3, w)
#undef BCOL
        }

        // ---- stage A(kt): 256 rows x 128B ----
        if constexpr (PRE) {
            const unsigned char* srcb = wc + (size_t)o0 * 2048 + kt * 128;
            const int sub = (t & 7) * 16;
            const int rbase = t >> 3;
#pragma unroll
            for (int j = 0; j < 8; ++j) {
                const int row = j * 32 + rbase;
                void* dstu = lds + j * 4096 + wid * 1024;  // wave-uniform base
                GLD_LDS16(srcb + (size_t)row * 2048 + sub, dstu);
            }
        } else {
            const float* p = wp + (size_t)(o0 + t) * CCH + kt * 32;
            float4 av[8];
#pragma unroll
            for (int r = 0; r < 8; ++r) av[r] = *(const float4*)(p + 4 * r);
            unsigned char* rowa = lds + t * 128;
#pragma unroll
            for (int oc = 0; oc < 4; ++oc) {
                unsigned h0, w0, h1, w1, h2, w2, h3, w3;
                cvt2(av[2*oc].x,   av[2*oc].y,   h0, w0);
                cvt2(av[2*oc].z,   av[2*oc].w,   h1, w1);
                cvt2(av[2*oc+1].x, av[2*oc+1].y, h2, w2);
                cvt2(av[2*oc+1].z, av[2*oc+1].w, h3, w3);
                *(uint4*)(rowa + physlot(oc, t) * 16)     = make_uint4(h0, h1, h2, h3);
                *(uint4*)(rowa + physlot(4 + oc, t) * 16) = make_uint4(w0, w1, w2, w3);
            }
        }

        asm volatile("" ::: "memory");

        // ---- prefetch B(kt+1) into regs; counted vmcnt keeps it in flight ----
        if (kt + 1 < NKT) {
            const float* p = inB + (size_t)((kt + 1) * 32 + kg * 4) * HW;
#pragma unroll
            for (int r = 0; r < 4; ++r) bn[r] = *(const float4*)(p + (size_t)r * HW);
            if constexpr (PRE) asm volatile("s_waitcnt vmcnt(4)" ::: "memory");
        } else {
            if constexpr (PRE) asm volatile("s_waitcnt vmcnt(0)" ::: "memory");
        }
        asm volatile("s_waitcnt lgkmcnt(0)" ::: "memory");
        __builtin_amdgcn_s_barrier();
        asm volatile("" ::: "memory");

        // ---- fragments + MFMA ----
        short8v bfh[4], bfl[4];
#pragma unroll
        for (int g = 0; g < 4; ++g) {
            const int n = wn * 64 + g * 16 + l15;
            const unsigned char* rb = ldsB + n * 128;
            bfh[g] = *(const short8v*)(rb + physlot(lko, n) * 16);
            bfl[g] = *(const short8v*)(rb + physlot(4 + lko, n) * 16);
        }
#pragma unroll
        for (int fh = 0; fh < 2; ++fh) {
            short8v ah[4], al[4];
#pragma unroll
            for (int fi = 0; fi < 4; ++fi) {
                const int r = wm * 128 + (fh * 4 + fi) * 16 + l15;
                const unsigned char* ra = lds + r * 128;
                ah[fi] = *(const short8v*)(ra + physlot(lko, r) * 16);
                al[fi] = *(const short8v*)(ra + physlot(4 + lko, r) * 16);
            }
#pragma unroll
            for (int fi = 0; fi < 4; ++fi)
#pragma unroll
                for (int g = 0; g < 4; ++g) {
                    f32x4 c = acc[fh * 4 + fi][g];
                    c = __builtin_amdgcn_mfma_f32_16x16x32_bf16(ah[fi], bfh[g], c, 0, 0, 0);
                    c = __builtin_amdgcn_mfma_f32_16x16x32_bf16(al[fi], bfh[g], c, 0, 0, 0);
                    c = __builtin_amdgcn_mfma_f32_16x16x32_bf16(ah[fi], bfl[g], c, 0, 0, 0);
                    acc[fh * 4 + fi][g] = c;
                }
        }

        asm volatile("" ::: "memory");
        __builtin_amdgcn_s_barrier();
        asm volatile("" ::: "memory");

#pragma unroll
        for (int r = 0; r < 4; ++r) bc[r] = bn[r];
    }

    // ---- epilogue: bias + store (C: row = lko*4+rg, col = l15) ----
    float* dstb = (ot < 2) ? gate : scan;
    const int c0 = o0 & (CCH - 1);
#pragma unroll
    for (int f = 0; f < 8; ++f) {
        const int rowb = wm * 128 + f * 16 + lko * 4;
#pragma unroll
        for (int rg = 0; rg < 4; ++rg) {
            const int o = o0 + rowb + rg;
            const float bias = bp[o];
            float* drow = dstb + ((size_t)b * CCH + c0 + rowb + rg) * HW;
#pragma unroll
            for (int g = 0; g < 4; ++g) {
                const int n = n0 + wn * 64 + g * 16 + l15;
                if (n < HW) drow[n] = acc[f][g][rg] + bias;
            }
        }
    }
}

// ---------------------------------------------------------------------------
// K2: per-(b,c) 2D discounted scan + fused epilogue (R0-proven).
// ---------------------------------------------------------------------------
__global__ __launch_bounds__(64) void scan_fuse(
    const float* __restrict__ in,
    const float* __restrict__ scanb,
    const float* __restrict__ disc,
    const float* __restrict__ gamma,
    float* gate_out)
{
    const int idx = blockIdx.x;
    const int c = idx & (CCH - 1);
    const size_t base = (size_t)idx * HW;
    const float d = disc[c];
    const float g = gamma[0];
    const int lane = threadIdx.x;

    __shared__ float L[WDIM * 57];

    if (lane < WDIM) {
        const int w = lane;
        float acc = 0.f;
#pragma unroll 4
        for (int h = 0; h < WDIM; h++) {
            acc = fmaf(d, acc, scanb[base + h * WDIM + w]);
            L[h * 57 + w] = acc;
        }
    }
    __syncthreads();
    if (lane < WDIM) {
        const int h = lane;
        float acc = 0.f;
#pragma unroll 4
        for (int w = 0; w < WDIM; w++) {
            acc = fmaf(d, acc, L[h * 57 + w]);
            L[h * 57 + w] = acc;
        }
    }
    __syncthreads();
    if (lane < WDIM) {
        const int w = lane;
#pragma unroll 4
        for (int h = 0; h < WDIM; h++) {
            const size_t off = base + h * WDIM + w;
            const float xc = L[h * 57 + w];
            const float sg = 1.f / (1.f + __expf(-xc));
            const float val = fmaf(g * gate_out[off], sg, in[off]);
            gate_out[off] = val;
        }
    }
}

extern "C" void kernel_launch(void* const* d_in, const int* in_sizes, int n_in,
                              void* d_out, int out_size, void* d_ws, size_t ws_size,
                              hipStream_t stream) {
    const float* in = (const float*)d_in[0];
    const float* wp = (const float*)d_in[1];
    const float* bp = (const float*)d_in[2];
    const float* dc = (const float*)d_in[3];
    const float* gm = (const float*)d_in[4];
    float* out = (float*)d_out;

    const size_t scan_bytes = (size_t)BATCH * CCH * HW * 4;   // 205.5 MB
    const size_t wcvt_bytes = (size_t)OCH * CCH * 4;          // 2 MB
    const bool pre = ws_size >= scan_bytes + wcvt_bytes;

    unsigned char* wcvt = (unsigned char*)d_ws;
    float* scanp = (float*)((unsigned char*)d_ws + (pre ? wcvt_bytes : 0));

    if (pre) {
        preconv_w<<<64, 256, 0, stream>>>(wp, wcvt);
        gemm_mfma<true><<<3200, 256, 0, stream>>>(in, wp, wcvt, bp, out, scanp);
    } else {
        gemm_mfma<false><<<3200, 256, 0, stream>>>(in, wp, wcvt, bp, out, scanp);
    }

    scan_fuse<<<BATCH * CCH, 64, 0, stream>>>(in, scanp, dc, gm, out);
}

// Round 5
// 667.590 us; speedup vs baseline: 3.3019x; 3.3019x over previous
//
#include <hip/hip_runtime.h>
#include <cstddef>
#include <cstdint>

#define BATCH 32
#define CCH   512
#define OCH   1024
#define HW    3136
#define WDIM  56
#define NKT   16           // 512 / BK, BK=32

typedef __attribute__((ext_vector_type(8))) short short8v;  // 8 bf16
typedef __attribute__((ext_vector_type(4))) float f32x4;

// pair of fp32 -> packed bf16 hi-word + lo-word (R1-proven numerics).
static __device__ __forceinline__ void cvt2(float x0, float x1,
                                            unsigned& hw, unsigned& lw) {
    unsigned u0 = __float_as_uint(x0), u1 = __float_as_uint(x1);
    hw = (u1 & 0xffff0000u) | (u0 >> 16);
    float l0 = x0 - __uint_as_float(u0 & 0xffff0000u);
    float l1 = x1 - __uint_as_float(u1 & 0xffff0000u);
    unsigned r0 = __float_as_uint(l0), r1 = __float_as_uint(l1);
    r0 = r0 + 0x7fffu + ((r0 >> 16) & 1u);
    r1 = r1 + 0x7fffu + ((r1 >> 16) & 1u);
    lw = (r1 & 0xffff0000u) | (r0 >> 16);
}

static __device__ __forceinline__ int physlot(int s, int row) {
    return (s ^ (row & 7) ^ ((row >> 3) & 7)) & 7;
}

#define GLD_LDS16(gsrc, ldst) \
    __builtin_amdgcn_global_load_lds( \
        (const __attribute__((address_space(1))) void*)(gsrc), \
        (__attribute__((address_space(3))) void*)(ldst), 16, 0, 0)

// ---------------------------------------------------------------------------
// K0: pre-convert weights into LDS-image layout (R3-proven).
// ---------------------------------------------------------------------------
__global__ __launch_bounds__(256) void preconv_w(
    const float* __restrict__ wp, unsigned char* __restrict__ wcvt)
{
    const int id = blockIdx.x * 256 + threadIdx.x;   // 16384 = 1024 o x 16 kt
    const int o = id >> 4, kt = id & 15;
    const float* p = wp + (size_t)o * CCH + kt * 32;
    unsigned char* dst = wcvt + (size_t)o * 2048 + kt * 128;
    float4 v[8];
#pragma unroll
    for (int r = 0; r < 8; ++r) v[r] = *(const float4*)(p + 4 * r);
#pragma unroll
    for (int oc = 0; oc < 4; ++oc) {
        unsigned h0, w0, h1, w1, h2, w2, h3, w3;
        cvt2(v[2*oc].x,   v[2*oc].y,   h0, w0);
        cvt2(v[2*oc].z,   v[2*oc].w,   h1, w1);
        cvt2(v[2*oc+1].x, v[2*oc+1].y, h2, w2);
        cvt2(v[2*oc+1].z, v[2*oc+1].w, h3, w3);
        *(uint4*)(dst + physlot(oc, o) * 16)     = make_uint4(h0, h1, h2, h3);
        *(uint4*)(dst + physlot(4 + oc, o) * 16) = make_uint4(w0, w1, w2, w3);
    }
}

// ---------------------------------------------------------------------------
// K1: MFMA GEMM, tile 512(o) x 128(n), BK=32, 512 threads = 8 waves (4x2 of
// 128x64). R3 addressing kept verbatim; NEW: full LDS double-buffer (A 64Kx2,
// B 16Kx2 = 160 KB), stage(kt+1) issued BEFORE MFMA(kt), ONE barrier per
// K-step with counted vmcnt(2) so B-prefetch loads cross the barrier.
// Grid (25, 2, 32) natural order (R3-proven L2 locality; R4 swizzle thrashed).
// ---------------------------------------------------------------------------
template <bool PRE>
__global__ __launch_bounds__(512, 2) void gemm_mfma(
    const float* __restrict__ in,          // [B,512,3136]
    const float* __restrict__ wp,          // [1024,512] (fallback path)
    const unsigned char* __restrict__ wc,  // wcvt (fast path)
    const float* __restrict__ bp,          // [1024]
    float* __restrict__ gate,              // d_out
    float* __restrict__ scan)              // ws (+2MB on fast path)
{
    const int bx = blockIdx.x;   // 0..24 n-tiles of 128 (last is half)
    const int by = blockIdx.y;   // 0: gate, 1: scan
    const int b  = blockIdx.z;
    const int t  = threadIdx.x;
    const int lane = t & 63;
    const int wid  = t >> 6;           // 0..7
    const int wm = wid >> 1;           // o-strip of 128
    const int wn = wid & 1;            // n-strip of 64
    const int l15 = lane & 15, lko = lane >> 4;

    __shared__ __align__(16) unsigned char lds[163840];  // A:0,64K  B:128K,144K

    const int o0 = by * 512;
    const int n0 = bx * 128;

    // B staging role: thread (q = n-quad, kk = k-pair)
    const int q  = t & 31;
    const int kk = t >> 5;             // 0..15
    const int maxq = ((HW - n0) >> 2) - 1;
    const int qc = q < maxq ? q : maxq;
    const float* inB = in + (size_t)b * (CCH * (size_t)HW) + n0 + 4 * qc;

    f32x4 acc[8][4] = {};
    float4 bc0, bc1;

    auto loadB = [&](int kt) {
        const float* p = inB + (size_t)(kt * 32 + 2 * kk) * HW;
        bc0 = *(const float4*)p;
        bc1 = *(const float4*)(p + HW);
    };

    auto writeB = [&](unsigned char* ldsB) {
        const int oc = kk >> 2, j4 = (kk & 3) * 4;
        unsigned hw_, lw_;
#define BCOL(C, COMP) \
        { const int nl = 4 * q + C; \
          unsigned char* row = ldsB + nl * 128; \
          cvt2(bc0.COMP, bc1.COMP, hw_, lw_); \
          *(unsigned*)(row + physlot(oc, nl) * 16 + j4)     = hw_; \
          *(unsigned*)(row + physlot(4 + oc, nl) * 16 + j4) = lw_; }
        BCOL(0, x) BCOL(1, y) BCOL(2, z) BCOL(3, w)
#undef BCOL
    };

    auto stageA = [&](int kt, unsigned char* ldsA) {
        if constexpr (PRE) {
            const unsigned char* srcb = wc + (size_t)o0 * 2048 + kt * 128;
            const int sub = (t & 7) * 16;
            const int rbase = t >> 3;
#pragma unroll
            for (int j = 0; j < 8; ++j) {
                const int row = j * 64 + rbase;
                void* dstu = ldsA + j * 8192 + wid * 1024;  // wave-uniform base
                GLD_LDS16(srcb + (size_t)row * 2048 + sub, dstu);
            }
        } else {
            const float* p = wp + (size_t)(o0 + t) * CCH + kt * 32;
            float4 av[8];
#pragma unroll
            for (int r = 0; r < 8; ++r) av[r] = *(const float4*)(p + 4 * r);
            unsigned char* rowa = ldsA + t * 128;
#pragma unroll
            for (int oc = 0; oc < 4; ++oc) {
                unsigned h0, w0, h1, w1, h2, w2, h3, w3;
                cvt2(av[2*oc].x,   av[2*oc].y,   h0, w0);
                cvt2(av[2*oc].z,   av[2*oc].w,   h1, w1);
                cvt2(av[2*oc+1].x, av[2*oc+1].y, h2, w2);
                cvt2(av[2*oc+1].z, av[2*oc+1].w, h3, w3);
                *(uint4*)(rowa + physlot(oc, t) * 16)     = make_uint4(h0, h1, h2, h3);
                *(uint4*)(rowa + physlot(4 + oc, t) * 16) = make_uint4(w0, w1, w2, w3);
            }
        }
    };

    // ---- prologue: fill buffer 0, prefetch B(1) regs ----
    loadB(0);
    writeB(lds + 131072);
    stageA(0, lds);
    loadB(1);
    if constexpr (PRE) asm volatile("s_waitcnt vmcnt(2)" ::: "memory");
    asm volatile("s_waitcnt lgkmcnt(0)" ::: "memory");
    __builtin_amdgcn_s_barrier();
    asm volatile("" ::: "memory");

#pragma unroll 1
    for (int kt = 0; kt < NKT; ++kt) {
        unsigned char* ldsAc = lds + (kt & 1) * 65536;
        unsigned char* ldsBc = lds + 131072 + (kt & 1) * 16384;
        unsigned char* ldsAn = lds + ((kt + 1) & 1) * 65536;
        unsigned char* ldsBn = lds + 131072 + ((kt + 1) & 1) * 16384;

        // ---- phase 1: issue next-tile staging (overlaps with MFMA below) ----
        if (kt + 1 < NKT) {
            writeB(ldsBn);                    // regs hold B(kt+1)
            stageA(kt + 1, ldsAn);            // 8x global_load_lds in flight
            if (kt + 2 < NKT) loadB(kt + 2);  // B regs for next round
        }

        // ---- phase 2: fragments + MFMA on current buffers ----
        short8v bfh[4], bfl[4];
#pragma unroll
        for (int g = 0; g < 4; ++g) {
            const int n = wn * 64 + g * 16 + l15;
            const unsigned char* rb = ldsBc + n * 128;
            bfh[g] = *(const short8v*)(rb + physlot(lko, n) * 16);
            bfl[g] = *(const short8v*)(rb + physlot(4 + lko, n) * 16);
        }
#pragma unroll
        for (int fh = 0; fh < 2; ++fh) {
            short8v ah[4], al[4];
#pragma unroll
            for (int fi = 0; fi < 4; ++fi) {
                const int r = wm * 128 + (fh * 4 + fi) * 16 + l15;
                const unsigned char* ra = ldsAc + r * 128;
                ah[fi] = *(const short8v*)(ra + physlot(lko, r) * 16);
                al[fi] = *(const short8v*)(ra + physlot(4 + lko, r) * 16);
            }
#pragma unroll
            for (int fi = 0; fi < 4; ++fi)
#pragma unroll
                for (int g = 0; g < 4; ++g) {
                    f32x4 c = acc[fh * 4 + fi][g];
                    c = __builtin_amdgcn_mfma_f32_16x16x32_bf16(ah[fi], bfh[g], c, 0, 0, 0);
                    c = __builtin_amdgcn_mfma_f32_16x16x32_bf16(al[fi], bfh[g], c, 0, 0, 0);
                    c = __builtin_amdgcn_mfma_f32_16x16x32_bf16(ah[fi], bfl[g], c, 0, 0, 0);
                    acc[fh * 4 + fi][g] = c;
                }
        }

        // ---- single barrier per K-step; counted vmcnt keeps B loads live ----
        if (kt + 1 < NKT) {
            if constexpr (PRE) {
                if (kt + 2 < NKT) asm volatile("s_waitcnt vmcnt(2)" ::: "memory");
                else              asm volatile("s_waitcnt vmcnt(0)" ::: "memory");
            }
            asm volatile("s_waitcnt lgkmcnt(0)" ::: "memory");
            __builtin_amdgcn_s_barrier();
            asm volatile("" ::: "memory");
        }
    }

    // ---- epilogue: bias + store (C: row = lko*4+rg, col = l15) ----
    float* dstb = (by == 0) ? gate : scan;
#pragma unroll
    for (int f = 0; f < 8; ++f) {
        const int rowb = wm * 128 + f * 16 + lko * 4;
#pragma unroll
        for (int rg = 0; rg < 4; ++rg) {
            const int o = o0 + rowb + rg;
            const float bias = bp[o];
            float* drow = dstb + ((size_t)b * CCH + (o & (CCH - 1))) * HW;
#pragma unroll
            for (int g = 0; g < 4; ++g) {
                const int n = n0 + wn * 64 + g * 16 + l15;
                if (n < HW) drow[n] = acc[f][g][rg] + bias;
            }
        }
    }
}

// ---------------------------------------------------------------------------
// K2: per-(b,c) 2D discounted scan + fused epilogue (R0-proven).
// ---------------------------------------------------------------------------
__global__ __launch_bounds__(64) void scan_fuse(
    const float* __restrict__ in,
    const float* __restrict__ scanb,
    const float* __restrict__ disc,
    const float* __restrict__ gamma,
    float* gate_out)
{
    const int idx = blockIdx.x;
    const int c = idx & (CCH - 1);
    const size_t base = (size_t)idx * HW;
    const float d = disc[c];
    const float g = gamma[0];
    const int lane = threadIdx.x;

    __shared__ float L[WDIM * 57];

    if (lane < WDIM) {
        const int w = lane;
        float acc = 0.f;
#pragma unroll 4
        for (int h = 0; h < WDIM; h++) {
            acc = fmaf(d, acc, scanb[base + h * WDIM + w]);
            L[h * 57 + w] = acc;
        }
    }
    __syncthreads();
    if (lane < WDIM) {
        const int h = lane;
        float acc = 0.f;
#pragma unroll 4
        for (int w = 0; w < WDIM; w++) {
            acc = fmaf(d, acc, L[h * 57 + w]);
            L[h * 57 + w] = acc;
        }
    }
    __syncthreads();
    if (lane < WDIM) {
        const int w = lane;
#pragma unroll 4
        for (int h = 0; h < WDIM; h++) {
            const size_t off = base + h * WDIM + w;
            const float xc = L[h * 57 + w];
            const float sg = 1.f / (1.f + __expf(-xc));
            const float val = fmaf(g * gate_out[off], sg, in[off]);
            gate_out[off] = val;
        }
    }
}

extern "C" void kernel_launch(void* const* d_in, const int* in_sizes, int n_in,
                              void* d_out, int out_size, void* d_ws, size_t ws_size,
                              hipStream_t stream) {
    const float* in = (const float*)d_in[0];
    const float* wp = (const float*)d_in[1];
    const float* bp = (const float*)d_in[2];
    const float* dc = (const float*)d_in[3];
    const float* gm = (const float*)d_in[4];
    float* out = (float*)d_out;

    const size_t scan_bytes = (size_t)BATCH * CCH * HW * 4;   // 205.5 MB
    const size_t wcvt_bytes = (size_t)OCH * CCH * 4;          // 2 MB
    const bool pre = ws_size >= scan_bytes + wcvt_bytes;

    unsigned char* wcvt = (unsigned char*)d_ws;
    float* scanp = (float*)((unsigned char*)d_ws + (pre ? wcvt_bytes : 0));

    dim3 g1(25, 2, BATCH);
    if (pre) {
        preconv_w<<<64, 256, 0, stream>>>(wp, wcvt);
        gemm_mfma<true><<<g1, 512, 0, stream>>>(in, wp, wcvt, bp, out, scanp);
    } else {
        gemm_mfma<false><<<g1, 512, 0, stream>>>(in, wp, wcvt, bp, out, scanp);
    }

    scan_fuse<<<BATCH * CCH, 64, 0, stream>>>(in, scanp, dc, gm, out);
}

// Round 6
// 656.867 us; speedup vs baseline: 3.3558x; 1.0163x over previous
//
#include <hip/hip_runtime.h>
#include <cstddef>
#include <cstdint>

#define BATCH 32
#define CCH   512
#define OCH   1024
#define HW    3136
#define WDIM  56
#define NKT   16           // 512 / BK, BK=32

typedef __attribute__((ext_vector_type(8))) short short8v;  // 8 bf16
typedef __attribute__((ext_vector_type(4))) float f32x4;

// pair of fp32 -> packed bf16 hi-word + lo-word (R1-proven numerics).
static __device__ __forceinline__ void cvt2(float x0, float x1,
                                            unsigned& hw, unsigned& lw) {
    unsigned u0 = __float_as_uint(x0), u1 = __float_as_uint(x1);
    hw = (u1 & 0xffff0000u) | (u0 >> 16);
    float l0 = x0 - __uint_as_float(u0 & 0xffff0000u);
    float l1 = x1 - __uint_as_float(u1 & 0xffff0000u);
    unsigned r0 = __float_as_uint(l0), r1 = __float_as_uint(l1);
    r0 = r0 + 0x7fffu + ((r0 >> 16) & 1u);
    r1 = r1 + 0x7fffu + ((r1 >> 16) & 1u);
    lw = (r1 & 0xffff0000u) | (r0 >> 16);
}

static __device__ __forceinline__ int physlot(int s, int row) {
    return (s ^ (row & 7) ^ ((row >> 3) & 7)) & 7;
}

#define GLD_LDS16(gsrc, ldst) \
    __builtin_amdgcn_global_load_lds( \
        (const __attribute__((address_space(1))) void*)(gsrc), \
        (__attribute__((address_space(3))) void*)(ldst), 16, 0, 0)

// ---------------------------------------------------------------------------
// K0: pre-convert weights into LDS-image layout (R3-proven).
// ---------------------------------------------------------------------------
__global__ __launch_bounds__(256) void preconv_w(
    const float* __restrict__ wp, unsigned char* __restrict__ wcvt)
{
    const int id = blockIdx.x * 256 + threadIdx.x;   // 16384 = 1024 o x 16 kt
    const int o = id >> 4, kt = id & 15;
    const float* p = wp + (size_t)o * CCH + kt * 32;
    unsigned char* dst = wcvt + (size_t)o * 2048 + kt * 128;
    float4 v[8];
#pragma unroll
    for (int r = 0; r < 8; ++r) v[r] = *(const float4*)(p + 4 * r);
#pragma unroll
    for (int oc = 0; oc < 4; ++oc) {
        unsigned h0, w0, h1, w1, h2, w2, h3, w3;
        cvt2(v[2*oc].x,   v[2*oc].y,   h0, w0);
        cvt2(v[2*oc].z,   v[2*oc].w,   h1, w1);
        cvt2(v[2*oc+1].x, v[2*oc+1].y, h2, w2);
        cvt2(v[2*oc+1].z, v[2*oc+1].w, h3, w3);
        *(uint4*)(dst + physlot(oc, o) * 16)     = make_uint4(h0, h1, h2, h3);
        *(uint4*)(dst + physlot(4 + oc, o) * 16) = make_uint4(w0, w1, w2, w3);
    }
}

// ---------------------------------------------------------------------------
// K1: MFMA GEMM, tile 512(o) x 128(n), BK=32, 512 threads = 8 waves (4x2 of
// 128x64). Dbuf LDS (A 64Kx2, B 16Kx2). Per kt: stage(kt+1) issued first,
// then fragment reads pipelined depth-2 under the MFMA stream (setprio'd),
// single barrier with CORRECT counted vmcnt(8) (only the A-DMA must drain;
// the 8 B-prefetch HBM loads stay in flight). kt-loop unrolled x2 so buffer
// pointers and LDS addresses are static.
// ---------------------------------------------------------------------------
template <bool PRE>
__global__ __launch_bounds__(512, 2) void gemm_mfma(
    const float* __restrict__ in,          // [B,512,3136]
    const float* __restrict__ wp,          // [1024,512] (fallback path)
    const unsigned char* __restrict__ wc,  // wcvt (fast path)
    const float* __restrict__ bp,          // [1024]
    float* __restrict__ gate,              // d_out
    float* __restrict__ scan)              // ws (+2MB on fast path)
{
    const int bx = blockIdx.x;   // 0..24 n-tiles of 128 (last is half)
    const int by = blockIdx.y;   // 0: gate, 1: scan
    const int b  = blockIdx.z;
    const int t  = threadIdx.x;
    const int lane = t & 63;
    const int wid  = t >> 6;           // 0..7
    const int wm = wid >> 1;           // o-strip of 128
    const int wn = wid & 1;            // n-strip of 64
    const int l15 = lane & 15, lko = lane >> 4;

    __shared__ __align__(16) unsigned char lds[163840];
    unsigned char* const ldsA0 = lds;
    unsigned char* const ldsA1 = lds + 65536;
    unsigned char* const ldsB0 = lds + 131072;
    unsigned char* const ldsB1 = lds + 147456;

    const int o0 = by * 512;
    const int n0 = bx * 128;

    // B staging role: thread (q = n-quad, kk = k-pair)
    const int q  = t & 31;
    const int kk = t >> 5;             // 0..15
    const int maxq = ((HW - n0) >> 2) - 1;
    const int qc = q < maxq ? q : maxq;
    const float* inB = in + (size_t)b * (CCH * (size_t)HW) + n0 + 4 * qc;

    f32x4 acc[8][4] = {};
    float4 bc0, bc1;

    auto loadB = [&](int kt) {
        const float* p = inB + (size_t)(kt * 32 + 2 * kk) * HW;
        bc0 = *(const float4*)p;
        bc1 = *(const float4*)(p + HW);
    };

    auto writeB = [&](unsigned char* ldsB) {
        const int oc = kk >> 2, j4 = (kk & 3) * 4;
        unsigned hw_, lw_;
#define BCOL(C, COMP) \
        { const int nl = 4 * q + C; \
          unsigned char* row = ldsB + nl * 128; \
          cvt2(bc0.COMP, bc1.COMP, hw_, lw_); \
          *(unsigned*)(row + physlot(oc, nl) * 16 + j4)     = hw_; \
          *(unsigned*)(row + physlot(4 + oc, nl) * 16 + j4) = lw_; }
        BCOL(0, x) BCOL(1, y) BCOL(2, z) BCOL(3, w)
#undef BCOL
    };

    auto stageA = [&](int kt, unsigned char* ldsA) {
        if constexpr (PRE) {
            const unsigned char* srcb = wc + (size_t)o0 * 2048 + kt * 128;
            const int sub = (t & 7) * 16;
            const int rbase = t >> 3;
#pragma unroll
            for (int j = 0; j < 8; ++j) {
                const int row = j * 64 + rbase;
                void* dstu = ldsA + j * 8192 + wid * 1024;  // wave-uniform base
                GLD_LDS16(srcb + (size_t)row * 2048 + sub, dstu);
            }
        } else {
            const float* p = wp + (size_t)(o0 + t) * CCH + kt * 32;
            float4 av[8];
#pragma unroll
            for (int r = 0; r < 8; ++r) av[r] = *(const float4*)(p + 4 * r);
            unsigned char* rowa = ldsA + t * 128;
#pragma unroll
            for (int oc = 0; oc < 4; ++oc) {
                unsigned h0, w0, h1, w1, h2, w2, h3, w3;
                cvt2(av[2*oc].x,   av[2*oc].y,   h0, w0);
                cvt2(av[2*oc].z,   av[2*oc].w,   h1, w1);
                cvt2(av[2*oc+1].x, av[2*oc+1].y, h2, w2);
                cvt2(av[2*oc+1].z, av[2*oc+1].w, h3, w3);
                *(uint4*)(rowa + physlot(oc, t) * 16)     = make_uint4(h0, h1, h2, h3);
                *(uint4*)(rowa + physlot(4 + oc, t) * 16) = make_uint4(w0, w1, w2, w3);
            }
        }
    };

    const int rbase0 = wm * 128 + l15;

    auto body = [&](int kt, unsigned char* Ac, unsigned char* An,
                    unsigned char* Bc, unsigned char* Bn) {
        const bool notlast = (kt + 1 < NKT);
        // ---- phase 1: issue next-tile staging (flies under the MFMAs) ----
        if (notlast) {
            writeB(Bn);                       // bc holds B(kt+1)
            stageA(kt + 1, An);               // 8x global_load_lds in flight
            if (kt + 2 < NKT) loadB(kt + 2);  // refill bc (in flight past barrier)
        }

        // ---- phase 2: B frags, then A-frag depth-2 pipeline under MFMA ----
        short8v bfh[4], bfl[4];
#pragma unroll
        for (int g = 0; g < 4; ++g) {
            const int n = wn * 64 + g * 16 + l15;
            const unsigned char* rb = Bc + n * 128;
            bfh[g] = *(const short8v*)(rb + physlot(lko, n) * 16);
            bfl[g] = *(const short8v*)(rb + physlot(4 + lko, n) * 16);
        }
#define A_H(FI) (*(const short8v*)(Ac + (size_t)(rbase0 + (FI) * 16) * 128 + \
                    physlot(lko, rbase0 + (FI) * 16) * 16))
#define A_L(FI) (*(const short8v*)(Ac + (size_t)(rbase0 + (FI) * 16) * 128 + \
                    physlot(4 + lko, rbase0 + (FI) * 16) * 16))
        short8v ahA = A_H(0), alA = A_L(0);
        short8v ahB, alB;
        __builtin_amdgcn_s_setprio(1);
#pragma unroll
        for (int fi = 0; fi < 8; ++fi) {
            if (fi + 1 < 8) {
                if ((fi & 1) == 0) { ahB = A_H(fi + 1); alB = A_L(fi + 1); }
                else               { ahA = A_H(fi + 1); alA = A_L(fi + 1); }
            }
            const short8v& ah = (fi & 1) ? ahB : ahA;
            const short8v& al = (fi & 1) ? alB : alA;
#pragma unroll
            for (int g = 0; g < 4; ++g) {
                f32x4 c = acc[fi][g];
                c = __builtin_amdgcn_mfma_f32_16x16x32_bf16(ah, bfh[g], c, 0, 0, 0);
                c = __builtin_amdgcn_mfma_f32_16x16x32_bf16(al, bfh[g], c, 0, 0, 0);
                c = __builtin_amdgcn_mfma_f32_16x16x32_bf16(ah, bfl[g], c, 0, 0, 0);
                acc[fi][g] = c;
            }
        }
        __builtin_amdgcn_s_setprio(0);
#undef A_H
#undef A_L

        // ---- single barrier; counted vmcnt: only A-DMA must drain ----
        if (notlast) {
            if constexpr (PRE) {
                if (kt + 2 < NKT) asm volatile("s_waitcnt vmcnt(8)" ::: "memory");
                else              asm volatile("s_waitcnt vmcnt(0)" ::: "memory");
            } else {
                asm volatile("s_waitcnt vmcnt(8)" ::: "memory");
            }
            asm volatile("s_waitcnt lgkmcnt(0)" ::: "memory");
            __builtin_amdgcn_s_barrier();
            asm volatile("" ::: "memory");
        }
    };

    // ---- prologue: fill buffer 0, prefetch B(1) regs ----
    loadB(0);
    writeB(ldsB0);
    stageA(0, ldsA0);
    loadB(1);
    if constexpr (PRE) asm volatile("s_waitcnt vmcnt(8)" ::: "memory");
    asm volatile("s_waitcnt lgkmcnt(0)" ::: "memory");
    __builtin_amdgcn_s_barrier();
    asm volatile("" ::: "memory");

#pragma unroll 1
    for (int kt2 = 0; kt2 < NKT; kt2 += 2) {
        body(kt2,     ldsA0, ldsA1, ldsB0, ldsB1);
        body(kt2 + 1, ldsA1, ldsA0, ldsB1, ldsB0);
    }

    // ---- epilogue: bias + store (C: row = lko*4+rg, col = l15) ----
    float* dstb = (by == 0) ? gate : scan;
#pragma unroll
    for (int f = 0; f < 8; ++f) {
        const int rowb = wm * 128 + f * 16 + lko * 4;
#pragma unroll
        for (int rg = 0; rg < 4; ++rg) {
            const int o = o0 + rowb + rg;
            const float bias = bp[o];
            float* drow = dstb + ((size_t)b * CCH + (o & (CCH - 1))) * HW;
#pragma unroll
            for (int g = 0; g < 4; ++g) {
                const int n = n0 + wn * 64 + g * 16 + l15;
                if (n < HW) drow[n] = acc[f][g][rg] + bias;
            }
        }
    }
}

// ---------------------------------------------------------------------------
// K2: per-(b,c) 2D discounted scan + fused epilogue (R0-proven).
// ---------------------------------------------------------------------------
__global__ __launch_bounds__(64) void scan_fuse(
    const float* __restrict__ in,
    const float* __restrict__ scanb,
    const float* __restrict__ disc,
    const float* __restrict__ gamma,
    float* gate_out)
{
    const int idx = blockIdx.x;
    const int c = idx & (CCH - 1);
    const size_t base = (size_t)idx * HW;
    const float d = disc[c];
    const float g = gamma[0];
    const int lane = threadIdx.x;

    __shared__ float L[WDIM * 57];

    if (lane < WDIM) {
        const int w = lane;
        float acc = 0.f;
#pragma unroll 4
        for (int h = 0; h < WDIM; h++) {
            acc = fmaf(d, acc, scanb[base + h * WDIM + w]);
            L[h * 57 + w] = acc;
        }
    }
    __syncthreads();
    if (lane < WDIM) {
        const int h = lane;
        float acc = 0.f;
#pragma unroll 4
        for (int w = 0; w < WDIM; w++) {
            acc = fmaf(d, acc, L[h * 57 + w]);
            L[h * 57 + w] = acc;
        }
    }
    __syncthreads();
    if (lane < WDIM) {
        const int w = lane;
#pragma unroll 4
        for (int h = 0; h < WDIM; h++) {
            const size_t off = base + h * WDIM + w;
            const float xc = L[h * 57 + w];
            const float sg = 1.f / (1.f + __expf(-xc));
            const float val = fmaf(g * gate_out[off], sg, in[off]);
            gate_out[off] = val;
        }
    }
}

extern "C" void kernel_launch(void* const* d_in, const int* in_sizes, int n_in,
                              void* d_out, int out_size, void* d_ws, size_t ws_size,
                              hipStream_t stream) {
    const float* in = (const float*)d_in[0];
    const float* wp = (const float*)d_in[1];
    const float* bp = (const float*)d_in[2];
    const float* dc = (const float*)d_in[3];
    const float* gm = (const float*)d_in[4];
    float* out = (float*)d_out;

    const size_t scan_bytes = (size_t)BATCH * CCH * HW * 4;   // 205.5 MB
    const size_t wcvt_bytes = (size_t)OCH * CCH * 4;          // 2 MB
    const bool pre = ws_size >= scan_bytes + wcvt_bytes;

    unsigned char* wcvt = (unsigned char*)d_ws;
    float* scanp = (float*)((unsigned char*)d_ws + (pre ? wcvt_bytes : 0));

    dim3 g1(25, 2, BATCH);
    if (pre) {
        preconv_w<<<64, 256, 0, stream>>>(wp, wcvt);
        gemm_mfma<true><<<g1, 512, 0, stream>>>(in, wp, wcvt, bp, out, scanp);
    } else {
        gemm_mfma<false><<<g1, 512, 0, stream>>>(in, wp, wcvt, bp, out, scanp);
    }

    scan_fuse<<<BATCH * CCH, 64, 0, stream>>>(in, scanp, dc, gm, out);
}